// Round 1
// baseline (1570.914 us; speedup 1.0000x reference)
//
#include <hip/hip_runtime.h>
#include <hip/hip_bf16.h>

#define N_ROWS 16384
#define DD 128
#define EPSV 1e-5f
#define SLOPE 0.2f
#define KSPLIT 4
#define KCHUNK (N_ROWS / KSPLIT)   // 4096
#define BK 64
#define MT 128

typedef short s16x8 __attribute__((ext_vector_type(8)));
typedef float f32x4 __attribute__((ext_vector_type(4)));

static __device__ inline unsigned short f2bf(float f) {
  union { __hip_bfloat16 h; unsigned short u; } cv;
  cv.h = __float2bfloat16(f);
  return cv.u;
}

// ---------------- Kernel 1: yT[d][i] = sum_k x[i,k] * W[k,d]  (bf16 out) ----
__global__ __launch_bounds__(256) void xw_kernel(const float* __restrict__ x,
                                                 const float* __restrict__ W,
                                                 unsigned short* __restrict__ yT) {
  const int t  = threadIdx.x;
  const int d  = t & 127;
  const int rh = t >> 7;              // 0..1 (wave-uniform)
  const int i0 = blockIdx.x * 8;
  float acc[4] = {0.f, 0.f, 0.f, 0.f};
  for (int k = 0; k < DD; ++k) {
    float wv = W[k * DD + d];
#pragma unroll
    for (int rr = 0; rr < 4; ++rr)
      acc[rr] = fmaf(x[(size_t)(i0 + rh + 2 * rr) * DD + k], wv, acc[rr]);
  }
#pragma unroll
  for (int rr = 0; rr < 4; ++rr)
    yT[(size_t)d * N_ROWS + i0 + rh + 2 * rr] = f2bf(acc[rr]);
}

// ---------------- Kernel 2: partial[ks] = A[:, ks-chunk] @ y[ks-chunk, :] ---
// 512 blocks (128 row-tiles x 4 K-splits), 256 threads = 4 waves (2x2),
// each wave 64x64 via 4x4 mfma_f32_16x16x32_bf16.
__global__ __launch_bounds__(256, 2) void gemm_kernel(const float* __restrict__ A,
                                                      const unsigned short* __restrict__ yT,
                                                      float* __restrict__ partial) {
  __shared__ unsigned short As[128][72];  // bf16, +8 pad -> 144B rows, conflict-free
  __shared__ unsigned short Bs[128][72];  // yT tile: [d][k]

  const int t   = threadIdx.x;
  const int bid = blockIdx.x;
  const int ks  = bid >> 7;     // 0..3
  const int rt  = bid & 127;    // row tile
  const int kbase0 = ks * KCHUNK;
  const int row0   = rt * MT;

  const int lane = t & 63;
  const int wid  = t >> 6;
  const int wr = wid >> 1, wc = wid & 1;
  const int mrow = lane & 15;
  const int quad = lane >> 4;

  const int sr = t >> 1;          // staging row (A) / column d (B)
  const int kh = (t & 1) * 32;    // k-half within BK=64

  f32x4 acc[4][4];
#pragma unroll
  for (int i = 0; i < 4; ++i)
#pragma unroll
    for (int j = 0; j < 4; ++j)
      acc[i][j] = (f32x4){0.f, 0.f, 0.f, 0.f};

  const int NKT = KCHUNK / BK;    // 64

  float4 av[8];
  uint4  bv[4];

  // prologue: load tile 0 into registers
  {
    const float4* ap = (const float4*)(A + (size_t)(row0 + sr) * N_ROWS + kbase0 + kh);
#pragma unroll
    for (int j = 0; j < 8; ++j) av[j] = ap[j];
    const uint4* bp = (const uint4*)(yT + (size_t)sr * N_ROWS + kbase0 + kh);
#pragma unroll
    for (int j = 0; j < 4; ++j) bv[j] = bp[j];
  }

  for (int kt = 0; kt < NKT; ++kt) {
    __syncthreads();  // previous compute done -> safe to overwrite LDS
    // convert A fp32 -> bf16, store; store B
#pragma unroll
    for (int q = 0; q < 4; ++q) {
      float4 f0 = av[2 * q], f1 = av[2 * q + 1];
      uint4 w;
      w.x = (unsigned int)f2bf(f0.x) | ((unsigned int)f2bf(f0.y) << 16);
      w.y = (unsigned int)f2bf(f0.z) | ((unsigned int)f2bf(f0.w) << 16);
      w.z = (unsigned int)f2bf(f1.x) | ((unsigned int)f2bf(f1.y) << 16);
      w.w = (unsigned int)f2bf(f1.z) | ((unsigned int)f2bf(f1.w) << 16);
      *(uint4*)&As[sr][kh + 8 * q] = w;
    }
#pragma unroll
    for (int j = 0; j < 4; ++j)
      *(uint4*)&Bs[sr][kh + 8 * j] = bv[j];
    __syncthreads();

    // prefetch next tile into registers: HBM busy during MFMA phase
    if (kt + 1 < NKT) {
      const int kb = kbase0 + (kt + 1) * BK;
      const float4* ap = (const float4*)(A + (size_t)(row0 + sr) * N_ROWS + kb + kh);
#pragma unroll
      for (int j = 0; j < 8; ++j) av[j] = ap[j];
      const uint4* bp = (const uint4*)(yT + (size_t)sr * N_ROWS + kb + kh);
#pragma unroll
      for (int j = 0; j < 4; ++j) bv[j] = bp[j];
    }

    // compute
#pragma unroll
    for (int ks2 = 0; ks2 < 2; ++ks2) {
      const int ko = ks2 * 32 + quad * 8;
      s16x8 af[4], bf[4];
#pragma unroll
      for (int mi = 0; mi < 4; ++mi)
        af[mi] = *(const s16x8*)&As[wr * 64 + mi * 16 + mrow][ko];
#pragma unroll
      for (int ni = 0; ni < 4; ++ni)
        bf[ni] = *(const s16x8*)&Bs[wc * 64 + ni * 16 + mrow][ko];
#pragma unroll
      for (int mi = 0; mi < 4; ++mi)
#pragma unroll
        for (int ni = 0; ni < 4; ++ni)
          acc[mi][ni] = __builtin_amdgcn_mfma_f32_16x16x32_bf16(af[mi], bf[ni],
                                                                acc[mi][ni], 0, 0, 0);
    }
  }

  // epilogue: C/D layout col=lane&15, row=quad*4+reg  [m89-verified]
  float* pout = partial + (size_t)ks * N_ROWS * DD;
#pragma unroll
  for (int mi = 0; mi < 4; ++mi)
#pragma unroll
    for (int ni = 0; ni < 4; ++ni)
#pragma unroll
      for (int r = 0; r < 4; ++r) {
        int gr = row0 + wr * 64 + mi * 16 + quad * 4 + r;
        int gc = wc * 64 + ni * 16 + mrow;
        pout[(size_t)gr * DD + gc] = acc[mi][ni][r];
      }
}

// ---------------- Kernel 3: Hsum = sum partials; column sum/sumsq ----------
__global__ __launch_bounds__(256) void sum_stats_kernel(const float* __restrict__ partial,
                                                        float* __restrict__ hsum,
                                                        float* __restrict__ stats) {
  __shared__ float s1[256], s2[256];
  const int t = threadIdx.x;
  const size_t base = (size_t)blockIdx.x * 8192;
  const float* p0 = partial;
  const float* p1 = partial + (size_t)N_ROWS * DD;
  const float* p2 = partial + 2 * (size_t)N_ROWS * DD;
  const float* p3 = partial + 3 * (size_t)N_ROWS * DD;
  float ls = 0.f, lq = 0.f;
#pragma unroll 4
  for (int i = 0; i < 32; ++i) {
    size_t e = base + t + 256 * (size_t)i;
    float v = p0[e] + p1[e] + p2[e] + p3[e];
    hsum[e] = v;
    ls += v;
    lq += v * v;
  }
  s1[t] = ls; s2[t] = lq;
  __syncthreads();
  if (t < 128) {  // col = t (256 = 2*128, partner t+128 has same column)
    atomicAdd(&stats[t], s1[t] + s1[t + 128]);
    atomicAdd(&stats[128 + t], s2[t] + s2[t + 128]);
  }
}

// ---------------- Kernel 3b: per-column scale/shift (b cancels under BN) ---
__global__ void finalize_stats_kernel(float* __restrict__ stats,
                                      const float* __restrict__ gamma,
                                      const float* __restrict__ beta) {
  int t = threadIdx.x;  // 0..127
  float mean = stats[t] * (1.0f / (float)N_ROWS);
  float var  = stats[128 + t] * (1.0f / (float)N_ROWS) - mean * mean;
  var = fmaxf(var, 0.f);
  float inv = rsqrtf(var + EPSV);
  float sc = gamma[t] * inv;
  stats[256 + t] = sc;
  stats[384 + t] = beta[t] - mean * sc;
}

// ---------------- Kernel 4: affine + LeakyReLU in place --------------------
__global__ __launch_bounds__(256) void norm_kernel(float* __restrict__ out,
                                                   const float* __restrict__ stats) {
  size_t e = (size_t)blockIdx.x * 256 + threadIdx.x;
  int col = (int)(e & 127);
  float v = out[e] * stats[256 + col] + stats[384 + col];
  out[e] = v >= 0.f ? v : SLOPE * v;
}

extern "C" void kernel_launch(void* const* d_in, const int* in_sizes, int n_in,
                              void* d_out, int out_size, void* d_ws, size_t ws_size,
                              hipStream_t stream) {
  const float* x     = (const float*)d_in[0];
  const float* A     = (const float*)d_in[1];
  const float* W     = (const float*)d_in[2];
  // d_in[3] = b : cancels exactly under BatchNorm mean subtraction
  const float* gamma = (const float*)d_in[4];
  const float* beta  = (const float*)d_in[5];
  float* out = (float*)d_out;

  char* ws = (char*)d_ws;
  unsigned short* yT = (unsigned short*)ws;                        // 4 MB
  float* partial = (float*)(ws + (size_t)4 * 1024 * 1024);         // 32 MB
  float* stats   = (float*)(ws + (size_t)36 * 1024 * 1024);        // 2 KB

  hipMemsetAsync(stats, 0, 512 * sizeof(float), stream);
  xw_kernel<<<N_ROWS / 8, 256, 0, stream>>>(x, W, yT);
  gemm_kernel<<<512, 256, 0, stream>>>(A, yT, partial);
  sum_stats_kernel<<<256, 256, 0, stream>>>(partial, out, stats);
  finalize_stats_kernel<<<1, 128, 0, stream>>>(stats, gamma, beta);
  norm_kernel<<<(N_ROWS * DD) / 256, 256, 0, stream>>>(out, stats);
}